// Round 4
// baseline (41.298 us; speedup 1.0000x reference)
//
#include <hip/hip_runtime.h>

// TiedCirculantSpectralFilter: B=512, D=1024, P=64, K=16, L_S=16
// Gram G[m,n] = sum_d X[d,m] * (gamma_d * X[d,n]) / 64  via bf16 MFMA,
// then 16-step iteration:
//   hp <- hp - (1/16) A hp   (A = G[:64,:64])
//   hk <- hk + (1/16) C hp   (C = G[64:80,:64])
//
// 640 threads (10 waves): waves 0-4 = k-half 0 + stage even chunks,
// waves 5-9 = k-half 1 + stage odd chunks. One barrier per chunk:
// stage writes buf[(c+1)&1] while compute reads buf[c&1] (disjoint).

namespace {
typedef __attribute__((ext_vector_type(8))) short bf16x8;
typedef __attribute__((ext_vector_type(4))) float f32x4;
typedef __attribute__((ext_vector_type(4))) float fv4;
typedef __attribute__((ext_vector_type(2))) unsigned uv2;

constexpr int kB  = 512;
constexpr int kD  = 1024;
constexpr int kP  = 64;
constexpr int kKK = 16;
constexpr int kLS = 16;
constexpr int kThreads = 640;           // 10 waves
constexpr int kKc = 64;                 // d-rows per chunk
constexpr int kNC = kD / kKc;           // 16 chunks

constexpr int TB    = 4096;             // gamma f32[1024] at byte 0
constexpr int ASZ   = 80 * 64 * 2;      // A tile [80 m][64 k] bf16, swizzled
constexpr int BSZ   = 64 * 64 * 2;      // B tile [64 n][64 k] bf16, gamma-weighted
constexpr int BUFSZ = ASZ + BSZ;        // 18432
constexpr int LDS_BYTES = TB + 2 * BUFSZ;  // 40960

__device__ __forceinline__ unsigned short bf16_bits(float x) {
  unsigned u = __builtin_bit_cast(unsigned, x);
  u += 0x7fffu + ((u >> 16) & 1u);   // round-to-nearest-even
  return (unsigned short)(u >> 16);
}
__device__ __forceinline__ unsigned bpack(float lo, float hi) {
  return (unsigned)bf16_bits(lo) | ((unsigned)bf16_bits(hi) << 16);
}

__global__ void __launch_bounds__(kThreads)
tcsf_kernel(const float* __restrict__ X, const float* __restrict__ y,
            const float* __restrict__ gamma, float* __restrict__ out) {
  __shared__ __align__(16) char smem[LDS_BYTES];
  float* gs = reinterpret_cast<float*>(smem);

  const int t = threadIdx.x;
  const int b = blockIdx.x;
  const int l = t & 63;
  const int w = t >> 6;                 // 0..9
  const int grp = (w >= 5) ? 1 : 0;     // stages chunks with c&1 == grp
  const int slab = grp ? (w - 5) : w;   // m-rows 16*slab..16*slab+15
  // group-local staging decomposition: 4 consecutive k x 4 consecutive m
  const int tg = grp ? (t - 320) : t;
  const int ct = tg % 20;               // m-quad
  const int kt = tg / 20;               // k-quad (0..15)

  for (int i = t; i < kD; i += kThreads) gs[i] = gamma[i];

  const fv4* Xg = reinterpret_cast<const fv4*>(X) + (size_t)b * (kD * 80 / 4);

  f32x4 acc[4];
#pragma unroll
  for (int nt = 0; nt < 4; ++nt) acc[nt] = (f32x4)(0.f);

  fv4 v0, v1, v2, v3;

  // fragment read addressing (constant per thread)
  const int rA   = 16 * slab + (l & 15);
  const int cb   = grp * 64 + (l >> 4) * 16;   // ks half + k-block
  const int fswz = (l & 7) << 4;               // row&7 == l&7 for both A and B rows

  // ---- prologue: both groups issue their first chunk's loads before barriers ----
  {
    const int c0 = grp;  // group0 -> chunk 0, group1 -> chunk 1
    const int base = (c0 * kKc + 4 * kt) * 20 + ct;
    v0 = Xg[base]; v1 = Xg[base + 20]; v2 = Xg[base + 40]; v3 = Xg[base + 60];
  }
  __syncthreads();  // gamma visible
  if (grp == 0) {   // stage chunk 0 -> buf0
    char* Ab = smem + TB;
    char* Bb = Ab + ASZ;
    const fv4 g4 = *reinterpret_cast<const fv4*>(gs + 4 * kt);
#pragma unroll
    for (int j = 0; j < 4; ++j) {
      const int m = 4 * ct + j;
      const int rowo = m * 128;
      const int col = (8 * kt) ^ ((m & 7) << 4);
      uv2 wa; wa.x = bpack(v0[j], v1[j]); wa.y = bpack(v2[j], v3[j]);
      *reinterpret_cast<uv2*>(Ab + rowo + col) = wa;
      if (ct < 16) {
        uv2 wb; wb.x = bpack(g4[0] * v0[j], g4[1] * v1[j]);
        wb.y = bpack(g4[2] * v2[j], g4[3] * v3[j]);
        *reinterpret_cast<uv2*>(Bb + rowo + col) = wb;
      }
    }
  }
  __syncthreads();  // buf0 staged

  // ---- main loop: one barrier per chunk ----
  for (int c = 0; c < kNC; ++c) {
    const int pl = c & 1;
    if (c + 2 < kNC && grp == pl) {  // issue loads for chunk c+2 (own regs free)
      const int base = ((c + 2) * kKc + 4 * kt) * 20 + ct;
      v0 = Xg[base]; v1 = Xg[base + 20]; v2 = Xg[base + 40]; v3 = Xg[base + 60];
    }
    if (c + 1 < kNC && grp != pl) {  // stage chunk c+1 -> buf[(c+1)&1]
      char* Ab = smem + TB + ((c + 1) & 1) * BUFSZ;
      char* Bb = Ab + ASZ;
      const fv4 g4 = *reinterpret_cast<const fv4*>(gs + (c + 1) * kKc + 4 * kt);
#pragma unroll
      for (int j = 0; j < 4; ++j) {
        const int m = 4 * ct + j;
        const int rowo = m * 128;
        const int col = (8 * kt) ^ ((m & 7) << 4);
        uv2 wa; wa.x = bpack(v0[j], v1[j]); wa.y = bpack(v2[j], v3[j]);
        *reinterpret_cast<uv2*>(Ab + rowo + col) = wa;
        if (ct < 16) {
          uv2 wb; wb.x = bpack(g4[0] * v0[j], g4[1] * v1[j]);
          wb.y = bpack(g4[2] * v2[j], g4[3] * v3[j]);
          *reinterpret_cast<uv2*>(Bb + rowo + col) = wb;
        }
      }
    }
    {  // compute chunk c from buf[c&1]: this wave's k-half, 4 MFMAs
      const char* Ab = smem + TB + pl * BUFSZ;
      const char* Bb = Ab + ASZ;
      const bf16x8 a = *reinterpret_cast<const bf16x8*>(Ab + rA * 128 + (cb ^ fswz));
#pragma unroll
      for (int nt = 0; nt < 4; ++nt) {
        const bf16x8 bb = *reinterpret_cast<const bf16x8*>(
            Bb + (16 * nt + (l & 15)) * 128 + (cb ^ fswz));
        acc[nt] = __builtin_amdgcn_mfma_f32_16x16x32_bf16(a, bb, acc[nt], 0, 0, 0);
      }
    }
    __syncthreads();
  }

  // ---- merge k-halves + G -> LDS ----
  // C/D layout: col = lane&15, row = (lane>>4)*4 + reg
  float* Gl = reinterpret_cast<float*>(smem + TB);  // [80][65] padded
  float* hp = Gl + 80 * 65;                         // hp[2][64]
  constexpr float invP = 1.0f / 64.0f;
  if (grp) {  // k-half 1 writes raw sums
#pragma unroll
    for (int nt = 0; nt < 4; ++nt)
#pragma unroll
      for (int r = 0; r < 4; ++r)
        Gl[(16 * slab + (l >> 4) * 4 + r) * 65 + 16 * nt + (l & 15)] = acc[nt][r];
  }
  __syncthreads();
  if (!grp) {  // k-half 0 adds, scales
#pragma unroll
    for (int nt = 0; nt < 4; ++nt)
#pragma unroll
      for (int r = 0; r < 4; ++r) {
        const int idx = (16 * slab + (l >> 4) * 4 + r) * 65 + 16 * nt + (l & 15);
        Gl[idx] = (Gl[idx] + acc[nt][r]) * invP;
      }
  }
  if (t < kP) hp[t] = y[b * kP + t];  // hp[0]
  __syncthreads();

  // ---- phase 2: 16 steps, 8 threads per row, hp double-buffered ----
  const int m = t >> 3;        // 0..79
  const int part = t & 7;
  const float* Grow = Gl + m * 65 + part * 8;
  float hk = 0.f;
  constexpr float invL = 1.0f / kLS;
  for (int s = 0; s < kLS; ++s) {
    const float* hpc = hp + (s & 1) * kP;
    const float* hpp = hpc + part * 8;
    float d0 = 0.f, d1 = 0.f, d2 = 0.f, d3 = 0.f;
#pragma unroll
    for (int i = 0; i < 8; i += 4) {
      d0 = fmaf(Grow[i + 0], hpp[i + 0], d0);
      d1 = fmaf(Grow[i + 1], hpp[i + 1], d1);
      d2 = fmaf(Grow[i + 2], hpp[i + 2], d2);
      d3 = fmaf(Grow[i + 3], hpp[i + 3], d3);
    }
    float dot = (d0 + d1) + (d2 + d3);
    dot += __shfl_xor(dot, 1);
    dot += __shfl_xor(dot, 2);
    dot += __shfl_xor(dot, 4);
    if (part == 0) {
      if (m < kP) hp[((s + 1) & 1) * kP + m] = hpc[m] - invL * dot;
      else        hk += invL * dot;
    }
    __syncthreads();
  }
  if (part == 0 && m >= kP) out[b * kKK + (m - kP)] = hk;
}

}  // namespace

extern "C" void kernel_launch(void* const* d_in, const int* in_sizes, int n_in,
                              void* d_out, int out_size, void* d_ws, size_t ws_size,
                              hipStream_t stream) {
  const float* X     = (const float*)d_in[0];  // [512,1024,80]
  const float* y     = (const float*)d_in[1];  // [512,64]
  const float* gamma = (const float*)d_in[2];  // [1024]
  float* out = (float*)d_out;                  // [512,16]
  tcsf_kernel<<<dim3(kB), dim3(kThreads), 0, stream>>>(X, y, gamma, out);
}

// Round 5
// 41.063 us; speedup vs baseline: 1.0057x; 1.0057x over previous
//
#include <hip/hip_runtime.h>

// TiedCirculantSpectralFilter: B=512, D=1024, P=64, K=16, L_S=16
// Gram G[m,n] = sum_d X[d,m] * (gamma_d * X[d,n]) / 64  via bf16 MFMA,
// then 16 steps: hp <- hp - (1/16) A hp ; hk <- hk + (1/16) C hp.
//
// 640 threads / 10 waves. Group g = waves 5g..5g+4 owns odd/even chunks.
// Per iteration c: group (c+1)&1 stages chunk c+1 (loads issued 2 iters ago,
// vmcnt-precise) then issues loads for chunk c+3; all waves MFMA chunk c;
// single barrier. LDS tiles use bijective swizzle f(m)=(m&7)^((m>>2)&7) on
// the 16B-slot bits -> staging writes ~conflict-free, frag reads 2-way free.

namespace {
typedef __attribute__((ext_vector_type(8))) short bf16x8;
typedef __attribute__((ext_vector_type(4))) float f32x4;
typedef __attribute__((ext_vector_type(4))) float fv4;
typedef __attribute__((ext_vector_type(2))) unsigned uv2;

constexpr int kB  = 512;
constexpr int kD  = 1024;
constexpr int kP  = 64;
constexpr int kKK = 16;
constexpr int kLS = 16;
constexpr int kThreads = 640;           // 10 waves
constexpr int kKc = 64;                 // d-rows per chunk
constexpr int kNC = kD / kKc;           // 16 chunks

constexpr int TB    = 4096;             // gamma f32[1024] at byte 0
constexpr int ASZ   = 80 * 128;         // A tile [80 m][64 k] bf16 (128 B rows)
constexpr int BSZ   = 64 * 128;         // B tile [64 n][64 k] bf16, gamma-weighted
constexpr int BUFSZ = ASZ + BSZ;        // 18432
constexpr int LDS_BYTES = TB + 2 * BUFSZ;  // 40960

__device__ __forceinline__ unsigned short bf16_bits(float x) {
  unsigned u = __builtin_bit_cast(unsigned, x);
  u += 0x7fffu + ((u >> 16) & 1u);   // round-to-nearest-even
  return (unsigned short)(u >> 16);
}
__device__ __forceinline__ unsigned bpack(float lo, float hi) {
  return (unsigned)bf16_bits(lo) | ((unsigned)bf16_bits(hi) << 16);
}
// bijective 16B-slot swizzle: spreads both consecutive-m (frag reads) and
// stride-4 m (staging writes) across all 8 slots of a 128-B row.
__device__ __forceinline__ int fswz(int r) {
  return ((r & 7) ^ ((r >> 2) & 7)) << 4;
}

__device__ __forceinline__ void stage_chunk(char* __restrict__ Ab, char* __restrict__ Bb,
                                            int ct, int kt,
                                            const fv4& v0, const fv4& v1,
                                            const fv4& v2, const fv4& v3,
                                            const fv4& g4) {
#pragma unroll
  for (int j = 0; j < 4; ++j) {
    const int m = 4 * ct + j;
    const int off = m * 128 + ((8 * kt) ^ fswz(m));
    uv2 wa; wa.x = bpack(v0[j], v1[j]); wa.y = bpack(v2[j], v3[j]);
    *reinterpret_cast<uv2*>(Ab + off) = wa;
    if (ct < 16) {
      uv2 wb; wb.x = bpack(g4[0] * v0[j], g4[1] * v1[j]);
      wb.y = bpack(g4[2] * v2[j], g4[3] * v3[j]);
      *reinterpret_cast<uv2*>(Bb + off) = wb;
    }
  }
}

__global__ void __launch_bounds__(kThreads)
tcsf_kernel(const float* __restrict__ X, const float* __restrict__ y,
            const float* __restrict__ gamma, float* __restrict__ out) {
  __shared__ __align__(16) char smem[LDS_BYTES];
  float* gs = reinterpret_cast<float*>(smem);

  const int t = threadIdx.x;
  const int b = blockIdx.x;
  const int l = t & 63;
  const int w = t >> 6;                 // 0..9
  const int grp = (w >= 5) ? 1 : 0;     // owns chunks with parity == grp
  const int slab = grp ? (w - 5) : w;   // m-rows 16*slab..+15
  const int tg = grp ? (t - 320) : t;
  const int ct = tg % 20;               // m-quad
  const int kt = tg / 20;               // k-quad (0..15)

  float yv = 0.f;
  if (t < kP) yv = y[b * kP + t];
  for (int i = t; i < kD; i += kThreads) gs[i] = gamma[i];

  const fv4* Xg = reinterpret_cast<const fv4*>(X) + (size_t)b * (kD * 80 / 4);

  f32x4 acc[4];
#pragma unroll
  for (int nt = 0; nt < 4; ++nt) acc[nt] = (f32x4)(0.f);

  fv4 v0, v1, v2, v3;

  // prologue: each group issues its first chunk's loads (g0: chunk 0, g1: chunk 1)
  {
    const int base = (grp * kKc + 4 * kt) * 20 + ct;
    v0 = Xg[base]; v1 = Xg[base + 20]; v2 = Xg[base + 40]; v3 = Xg[base + 60];
  }
  __syncthreads();  // gamma visible
  if (!grp) {       // stage chunk 0 -> buf0, then issue chunk 2
    const fv4 g4 = *reinterpret_cast<const fv4*>(gs + 4 * kt);
    stage_chunk(smem + TB, smem + TB + ASZ, ct, kt, v0, v1, v2, v3, g4);
    const int base = (2 * kKc + 4 * kt) * 20 + ct;
    v0 = Xg[base]; v1 = Xg[base + 20]; v2 = Xg[base + 40]; v3 = Xg[base + 60];
  }
  __syncthreads();  // buf0 staged

  // fragment read offsets (constant per thread)
  const int rA = 16 * slab + (l & 15);
  const int cbb = grp * 64 + (l >> 4) * 16;   // k-half + k-quad byte offset
  const int offA = rA * 128 + (cbb ^ fswz(rA));
  int offB[4];
#pragma unroll
  for (int nt = 0; nt < 4; ++nt) {
    const int rB = 16 * nt + (l & 15);
    offB[nt] = rB * 128 + (cbb ^ fswz(rB));
  }

  // main loop: one barrier per chunk; stage(c+1) + issue(c+3) on own turn
  for (int c = 0; c < kNC; ++c) {
    if (grp == ((c + 1) & 1)) {
      if (c + 1 < kNC) {
        const fv4 g4 = *reinterpret_cast<const fv4*>(gs + (c + 1) * kKc + 4 * kt);
        char* Ab = smem + TB + ((c + 1) & 1) * BUFSZ;
        stage_chunk(Ab, Ab + ASZ, ct, kt, v0, v1, v2, v3, g4);
      }
      if (c + 3 < kNC) {
        const int base = ((c + 3) * kKc + 4 * kt) * 20 + ct;
        v0 = Xg[base]; v1 = Xg[base + 20]; v2 = Xg[base + 40]; v3 = Xg[base + 60];
      }
    }
    const char* Ab = smem + TB + (c & 1) * BUFSZ;
    const char* Bb = Ab + ASZ;
    const bf16x8 a = *reinterpret_cast<const bf16x8*>(Ab + offA);
#pragma unroll
    for (int nt = 0; nt < 4; ++nt) {
      const bf16x8 bb = *reinterpret_cast<const bf16x8*>(Bb + offB[nt]);
      acc[nt] = __builtin_amdgcn_mfma_f32_16x16x32_bf16(a, bb, acc[nt], 0, 0, 0);
    }
    __syncthreads();
  }

  // ---- merge k-halves + G -> LDS ----
  // C/D layout: col = lane&15, row = (lane>>4)*4 + reg
  float* Gl = reinterpret_cast<float*>(smem + TB);  // [80][65] padded
  float* hp = Gl + 80 * 65;                         // hp[2][64]
  constexpr float invP = 1.0f / 64.0f;
  if (grp) {
#pragma unroll
    for (int nt = 0; nt < 4; ++nt)
#pragma unroll
      for (int r = 0; r < 4; ++r)
        Gl[(16 * slab + (l >> 4) * 4 + r) * 65 + 16 * nt + (l & 15)] = acc[nt][r];
  }
  __syncthreads();
  if (!grp) {
#pragma unroll
    for (int nt = 0; nt < 4; ++nt)
#pragma unroll
      for (int r = 0; r < 4; ++r) {
        const int idx = (16 * slab + (l >> 4) * 4 + r) * 65 + 16 * nt + (l & 15);
        Gl[idx] = (Gl[idx] + acc[nt][r]) * invP;
      }
  }
  if (t < kP) hp[t] = yv;  // hp[0]
  __syncthreads();

  // ---- phase 2: 16 steps, 8 threads per row, hp double-buffered ----
  const int m = t >> 3;        // 0..79
  const int part = t & 7;
  const float* Grow = Gl + m * 65 + part * 8;
  float hk = 0.f;
  constexpr float invL = 1.0f / kLS;
  for (int s = 0; s < kLS; ++s) {
    const float* hpc = hp + (s & 1) * kP;
    const float* hpp = hpc + part * 8;
    float d0 = 0.f, d1 = 0.f, d2 = 0.f, d3 = 0.f;
#pragma unroll
    for (int i = 0; i < 8; i += 4) {
      d0 = fmaf(Grow[i + 0], hpp[i + 0], d0);
      d1 = fmaf(Grow[i + 1], hpp[i + 1], d1);
      d2 = fmaf(Grow[i + 2], hpp[i + 2], d2);
      d3 = fmaf(Grow[i + 3], hpp[i + 3], d3);
    }
    float dot = (d0 + d1) + (d2 + d3);
    dot += __shfl_xor(dot, 1);
    dot += __shfl_xor(dot, 2);
    dot += __shfl_xor(dot, 4);
    if (part == 0) {
      if (m < kP) hp[((s + 1) & 1) * kP + m] = hpc[m] - invL * dot;
      else        hk += invL * dot;
    }
    __syncthreads();
  }
  if (part == 0 && m >= kP) out[b * kKK + (m - kP)] = hk;
}

}  // namespace

extern "C" void kernel_launch(void* const* d_in, const int* in_sizes, int n_in,
                              void* d_out, int out_size, void* d_ws, size_t ws_size,
                              hipStream_t stream) {
  const float* X     = (const float*)d_in[0];  // [512,1024,80]
  const float* y     = (const float*)d_in[1];  // [512,64]
  const float* gamma = (const float*)d_in[2];  // [1024]
  float* out = (float*)d_out;                  // [512,16]
  tcsf_kernel<<<dim3(kB), dim3(kThreads), 0, stream>>>(X, y, gamma, out);
}

// Round 6
// 40.224 us; speedup vs baseline: 1.0267x; 1.0208x over previous
//
#include <hip/hip_runtime.h>

// TiedCirculantSpectralFilter: B=512, D=1024, P=64, K=16, L_S=16
// Gram G[m,n] = sum_d X[d,m] * (gamma_d * X[d,n]) / 64  via bf16 MFMA,
// then 16 steps: hp <- hp - (1/16) A hp ; hk <- hk + (1/16) C hp.
//
// Producer/consumer wave specialization: 512 thr / 8 waves.
//  waves 0-2 (consumers): MFMA only. w0: m 0-31, w1: m 32-63 (16 MFMA/chunk),
//    w2: m 64-79 (8 MFMA/chunk). Full K=64 per chunk per wave -> B-frags
//    reused across 2 row-frags, no k-half merge.
//  waves 3-7 (producers): global f32 loads -> bf16 pack -> swizzled ds_write,
//    staging every chunk, regs loaded 1 iteration ahead. One barrier/chunk.

namespace {
typedef __attribute__((ext_vector_type(8))) short bf16x8;
typedef __attribute__((ext_vector_type(4))) float f32x4;
typedef __attribute__((ext_vector_type(4))) float fv4;
typedef __attribute__((ext_vector_type(2))) unsigned uv2;

constexpr int kB  = 512;
constexpr int kD  = 1024;
constexpr int kP  = 64;
constexpr int kPK = 80;
constexpr int kKK = 16;
constexpr int kLS = 16;
constexpr int kThreads = 512;           // 8 waves
constexpr int kKc = 64;                 // d-rows per chunk
constexpr int kNC = kD / kKc;           // 16 chunks

constexpr int TB    = 4096;             // gamma f32[1024] at byte 0
constexpr int ASZ   = 80 * 128;         // A tile [80 m][64 k] bf16, swizzled
constexpr int BSZ   = 64 * 128;         // B tile [64 n][64 k] bf16, gamma-weighted
constexpr int BUFSZ = ASZ + BSZ;        // 18432
constexpr int LDS_BYTES = TB + 2 * BUFSZ;  // 40960

__device__ __forceinline__ unsigned short bf16_bits(float x) {
  unsigned u = __builtin_bit_cast(unsigned, x);
  u += 0x7fffu + ((u >> 16) & 1u);   // round-to-nearest-even
  return (unsigned short)(u >> 16);
}
__device__ __forceinline__ unsigned bpack(float lo, float hi) {
  return (unsigned)bf16_bits(lo) | ((unsigned)bf16_bits(hi) << 16);
}
// bijective 16B-slot swizzle (bits [6:4] of the in-row byte col)
__device__ __forceinline__ int fswz(int r) {
  return ((r & 7) ^ ((r >> 2) & 7)) << 4;
}

__device__ __forceinline__ void stage_chunk(char* __restrict__ Ab, char* __restrict__ Bb,
                                            int ct, int kt,
                                            const fv4& v0, const fv4& v1,
                                            const fv4& v2, const fv4& v3,
                                            const fv4& g4) {
#pragma unroll
  for (int j = 0; j < 4; ++j) {
    const int m = 4 * ct + j;
    const int off = m * 128 + ((8 * kt) ^ fswz(m));
    uv2 wa; wa.x = bpack(v0[j], v1[j]); wa.y = bpack(v2[j], v3[j]);
    *reinterpret_cast<uv2*>(Ab + off) = wa;
    if (ct < 16) {
      uv2 wb; wb.x = bpack(g4[0] * v0[j], g4[1] * v1[j]);
      wb.y = bpack(g4[2] * v2[j], g4[3] * v3[j]);
      *reinterpret_cast<uv2*>(Bb + off) = wb;
    }
  }
}

__global__ void __launch_bounds__(kThreads, 4)
tcsf_kernel(const float* __restrict__ X, const float* __restrict__ y,
            const float* __restrict__ gamma, float* __restrict__ out) {
  __shared__ __align__(16) char smem[LDS_BYTES];
  float* gs = reinterpret_cast<float*>(smem);

  const int t = threadIdx.x;
  const int b = blockIdx.x;
  const int l = t & 63;
  const int w = t >> 6;                 // 0..7
  const bool producer = (w >= 3);

  float yv = 0.f;
  if (t < kP) yv = y[b * kP + t];
  for (int i = t; i < kD; i += kThreads) gs[i] = gamma[i];

  const fv4* Xg = reinterpret_cast<const fv4*>(X) + (size_t)b * (kD * 80 / 4);

  // producer decomposition (320 threads): 4 consecutive k x 4 consecutive m
  int ct = 0, kt = 0;
  fv4 v0, v1, v2, v3;
  if (producer) {
    const int tg = t - 192;
    ct = tg % 20;                       // m-quad
    kt = tg / 20;                       // k-quad 0..15
    const int base = (4 * kt) * 20 + ct;  // chunk 0
    v0 = Xg[base]; v1 = Xg[base + 20]; v2 = Xg[base + 40]; v3 = Xg[base + 60];
  }

  // consumer fragment state
  f32x4 acc[2][4];
#pragma unroll
  for (int f = 0; f < 2; ++f)
#pragma unroll
    for (int nt = 0; nt < 4; ++nt) acc[f][nt] = (f32x4)(0.f);
  int offA[2][2], offB[4][2];
  if (!producer) {
    const int lane15 = l & 15, kq = l >> 4;
    const int r00 = 32 * w;
#pragma unroll
    for (int f = 0; f < 2; ++f) {
      const int r = r00 + 16 * f + lane15;   // f=1 unused for w==2
#pragma unroll
      for (int ks = 0; ks < 2; ++ks)
        offA[f][ks] = r * 128 + ((ks * 64 + kq * 16) ^ fswz(r));
    }
#pragma unroll
    for (int nt = 0; nt < 4; ++nt) {
      const int r = 16 * nt + lane15;
#pragma unroll
      for (int ks = 0; ks < 2; ++ks)
        offB[nt][ks] = r * 128 + ((ks * 64 + kq * 16) ^ fswz(r));
    }
  }

  __syncthreads();  // gamma visible
  if (producer) {   // stage chunk 0 -> buf0, then issue chunk 1 loads
    const fv4 g4 = *reinterpret_cast<const fv4*>(gs + 4 * kt);
    stage_chunk(smem + TB, smem + TB + ASZ, ct, kt, v0, v1, v2, v3, g4);
    const int base = (kKc + 4 * kt) * 20 + ct;
    v0 = Xg[base]; v1 = Xg[base + 20]; v2 = Xg[base + 40]; v3 = Xg[base + 60];
  }
  __syncthreads();  // buf0 staged

  // ---- main loop: one barrier per chunk ----
  for (int c = 0; c < kNC; ++c) {
    if (producer) {
      if (c + 1 < kNC) {   // stage chunk c+1 (regs loaded last iter)
        const fv4 g4 = *reinterpret_cast<const fv4*>(gs + (c + 1) * kKc + 4 * kt);
        char* Ab = smem + TB + ((c + 1) & 1) * BUFSZ;
        stage_chunk(Ab, Ab + ASZ, ct, kt, v0, v1, v2, v3, g4);
      }
      if (c + 2 < kNC) {   // issue loads for chunk c+2
        const int base = ((c + 2) * kKc + 4 * kt) * 20 + ct;
        v0 = Xg[base]; v1 = Xg[base + 20]; v2 = Xg[base + 40]; v3 = Xg[base + 60];
      }
    } else {
      const char* Ab = smem + TB + (c & 1) * BUFSZ;
      const char* Bb = Ab + ASZ;
#pragma unroll
      for (int ks = 0; ks < 2; ++ks) {
        const bf16x8 a0 = *reinterpret_cast<const bf16x8*>(Ab + offA[0][ks]);
        bf16x8 a1 = a0;
        if (w < 2) a1 = *reinterpret_cast<const bf16x8*>(Ab + offA[1][ks]);
#pragma unroll
        for (int nt = 0; nt < 4; ++nt) {
          const bf16x8 bb = *reinterpret_cast<const bf16x8*>(Bb + offB[nt][ks]);
          acc[0][nt] = __builtin_amdgcn_mfma_f32_16x16x32_bf16(a0, bb, acc[0][nt], 0, 0, 0);
          if (w < 2)
            acc[1][nt] = __builtin_amdgcn_mfma_f32_16x16x32_bf16(a1, bb, acc[1][nt], 0, 0, 0);
        }
      }
    }
    __syncthreads();
  }

  // ---- G -> LDS (direct, no merge: each (m,n) owned by one wave) ----
  // C/D layout: col = lane&15, row = (lane>>4)*4 + reg
  float* Gl = reinterpret_cast<float*>(smem + TB);  // [80][65] padded
  float* hp = Gl + 80 * 65;                         // [64]
  constexpr float invP = 1.0f / 64.0f;
  if (!producer) {
    const int lane15 = l & 15, kq = l >> 4;
    const int nf = (w < 2) ? 2 : 1;
    for (int f = 0; f < nf; ++f)
#pragma unroll
      for (int nt = 0; nt < 4; ++nt)
#pragma unroll
        for (int r = 0; r < 4; ++r)
          Gl[(32 * w + 16 * f + kq * 4 + r) * 65 + 16 * nt + lane15] =
              acc[f][nt][r] * invP;
  }
  if (t < kP) hp[t] = yv;
  __syncthreads();

  // ---- phase 2: 16 steps, 4 threads per row (rows 0..79 = threads 0..319) ----
  const int m = t >> 2;        // 0..127; active iff m < 80 (wave-uniform split)
  const int part = t & 3;
  const bool act = (m < kPK);
  const float* Grow = Gl + m * 65 + part * 16;
  const float* hpp = hp + part * 16;
  float hk = 0.f;
  constexpr float invL = 1.0f / kLS;
  for (int s = 0; s < kLS; ++s) {
    float dot = 0.f;
    if (act) {
      float d0 = 0.f, d1 = 0.f, d2 = 0.f, d3 = 0.f;
#pragma unroll
      for (int i = 0; i < 16; i += 4) {
        d0 = fmaf(Grow[i + 0], hpp[i + 0], d0);
        d1 = fmaf(Grow[i + 1], hpp[i + 1], d1);
        d2 = fmaf(Grow[i + 2], hpp[i + 2], d2);
        d3 = fmaf(Grow[i + 3], hpp[i + 3], d3);
      }
      dot = (d0 + d1) + (d2 + d3);
      dot += __shfl_xor(dot, 1);
      dot += __shfl_xor(dot, 2);
    }
    __syncthreads();  // all reads of hp complete
    if (act && part == 0) {
      if (m < kP) hp[m] -= invL * dot;
      else        hk   += invL * dot;
    }
    __syncthreads();  // hp update visible
  }
  if (act && part == 0 && m >= kP) out[b * kKK + (m - kP)] = hk;
}

}  // namespace

extern "C" void kernel_launch(void* const* d_in, const int* in_sizes, int n_in,
                              void* d_out, int out_size, void* d_ws, size_t ws_size,
                              hipStream_t stream) {
  const float* X     = (const float*)d_in[0];  // [512,1024,80]
  const float* y     = (const float*)d_in[1];  // [512,64]
  const float* gamma = (const float*)d_in[2];  // [1024]
  float* out = (float*)d_out;                  // [512,16]
  tcsf_kernel<<<dim3(kB), dim3(kThreads), 0, stream>>>(X, y, gamma, out);
}